// Round 1
// baseline (263.309 us; speedup 1.0000x reference)
//
#include <hip/hip_runtime.h>
#include <hip/hip_bf16.h>

typedef _Float16 h8 __attribute__((ext_vector_type(8)));
typedef _Float16 h4 __attribute__((ext_vector_type(4)));
typedef float f4 __attribute__((ext_vector_type(4)));

#define N_TOK 65536
#define DIM 256
#define KCODES 1024
#define HWSZ 4096

// ---------------- K1: embedding prep: fp16 hi/lo split + e_sq ----------------
__global__ void k_prep(const float* __restrict__ emb, _Float16* __restrict__ eBh,
                       _Float16* __restrict__ eBl, float* __restrict__ e_sq) {
    int t = threadIdx.x;
    int code = blockIdx.x * 4 + (t >> 6);
    int l = t & 63;
    float4 v = *(const float4*)(emb + (size_t)code * DIM + l * 4);
    float s = v.x * v.x + v.y * v.y + v.z * v.z + v.w * v.w;
    float e[4] = {v.x, v.y, v.z, v.w};
    h4 hi, lo;
#pragma unroll
    for (int j = 0; j < 4; ++j) {
        _Float16 h = (_Float16)e[j];
        hi[j] = h;
        lo[j] = (_Float16)(e[j] - (float)h);
    }
    *(h4*)(eBh + (size_t)code * DIM + l * 4) = hi;
    *(h4*)(eBl + (size_t)code * DIM + l * 4) = lo;
#pragma unroll
    for (int off = 32; off >= 1; off >>= 1) s += __shfl_xor(s, off);
    if (l == 0) e_sq[code] = s;
}

// ---------------- K2: transpose z[B,C,H,W] -> encoded_flat[N,C] --------------
__global__ void k_transpose(const float* __restrict__ z, float* __restrict__ enc) {
    __shared__ float T[64][65];
    int blk = blockIdx.x;
    int b = blk >> 8;
    int rem = blk & 255;
    int c0 = (rem >> 6) * 64;
    int hw0 = (rem & 63) * 64;
    int t = threadIdx.x;
    const float* zp = z + (size_t)b * DIM * HWSZ;
    {
        int hw4 = (t & 15) * 4, cl = t >> 4;  // cl 0..15
#pragma unroll
        for (int i = 0; i < 4; ++i) {
            int c = cl + i * 16;
            float4 v = *(const float4*)(zp + (size_t)(c0 + c) * HWSZ + hw0 + hw4);
            T[c][hw4 + 0] = v.x; T[c][hw4 + 1] = v.y;
            T[c][hw4 + 2] = v.z; T[c][hw4 + 3] = v.w;
        }
    }
    __syncthreads();
    {
        int c4 = (t & 15) * 4, hwl = t >> 4;
#pragma unroll
        for (int i = 0; i < 4; ++i) {
            int hw = hwl + i * 16;
            float4 v;
            v.x = T[c4 + 0][hw]; v.y = T[c4 + 1][hw];
            v.z = T[c4 + 2][hw]; v.w = T[c4 + 3][hw];
            *(float4*)(enc + (size_t)(b * HWSZ + hw0 + hw) * DIM + c0 + c4) = v;
        }
    }
}

// ---------------- K3: GEMM (fp16 split, 3 passes) + fused argmin -------------
#define BM 128
#define BN 256
#define PAD 40

__global__ __launch_bounds__(512)
void k_gemm_argmin(const float* __restrict__ enc, const _Float16* __restrict__ eBh,
                   const _Float16* __restrict__ eBl, const float* __restrict__ e_sq,
                   float* __restrict__ partV, int* __restrict__ partI) {
    __shared__ _Float16 Ah[BM * PAD];
    __shared__ _Float16 Al[BM * PAD];
    __shared__ _Float16 Bh[BN * PAD];
    __shared__ _Float16 Bl[BN * PAD];

    int gid = blockIdx.x;
    int colTile = gid & 3, rowTile = gid >> 2;
    int r0 = rowTile * BM;
    int c0 = colTile * BN;
    int t = threadIdx.x;
    int w = t >> 6, l = t & 63;
    int wm = w >> 2, wn = w & 3;
    int l16 = l & 15, lhi = l >> 4;

    f4 acc[4][4];
#pragma unroll
    for (int i = 0; i < 4; ++i)
#pragma unroll
        for (int j = 0; j < 4; ++j) acc[i][j] = (f4)0.0f;

    for (int step = 0; step < 8; ++step) {
        int d0 = step * 32;
        // stage A (fp32 -> hi/lo fp16, reg-staged)
        {
            int arow = t >> 2, dq = t & 3;
            const float* src = enc + (size_t)(r0 + arow) * DIM + d0 + dq * 8;
            float4 x0 = *(const float4*)(src);
            float4 x1 = *(const float4*)(src + 4);
            float xs[8] = {x0.x, x0.y, x0.z, x0.w, x1.x, x1.y, x1.z, x1.w};
            h8 hi, lo;
#pragma unroll
            for (int j = 0; j < 8; ++j) {
                _Float16 h = (_Float16)xs[j];
                hi[j] = h;
                lo[j] = (_Float16)(xs[j] - (float)h);
            }
            *(h8*)(Ah + arow * PAD + dq * 8) = hi;
            *(h8*)(Al + arow * PAD + dq * 8) = lo;
        }
        // stage B (precomputed fp16 hi/lo)
#pragma unroll
        for (int ss = 0; ss < 2; ++ss) {
            int s = t + ss * 512;
            int code = s >> 2, dq = s & 3;
            size_t go = (size_t)(c0 + code) * DIM + d0 + dq * 8;
            h8 bhv = *(const h8*)(eBh + go);
            h8 blv = *(const h8*)(eBl + go);
            *(h8*)(Bh + code * PAD + dq * 8) = bhv;
            *(h8*)(Bl + code * PAD + dq * 8) = blv;
        }
        __syncthreads();
        h8 ah[4], al[4], bh[4], bl[4];
#pragma unroll
        for (int mf = 0; mf < 4; ++mf) {
            int arow = wm * 64 + mf * 16 + l16;
            ah[mf] = *(const h8*)(Ah + arow * PAD + lhi * 8);
            al[mf] = *(const h8*)(Al + arow * PAD + lhi * 8);
        }
#pragma unroll
        for (int nf = 0; nf < 4; ++nf) {
            int brow = wn * 64 + nf * 16 + l16;
            bh[nf] = *(const h8*)(Bh + brow * PAD + lhi * 8);
            bl[nf] = *(const h8*)(Bl + brow * PAD + lhi * 8);
        }
#pragma unroll
        for (int mf = 0; mf < 4; ++mf)
#pragma unroll
            for (int nf = 0; nf < 4; ++nf) {
                acc[mf][nf] = __builtin_amdgcn_mfma_f32_16x16x32_f16(ah[mf], bh[nf], acc[mf][nf], 0, 0, 0);
                acc[mf][nf] = __builtin_amdgcn_mfma_f32_16x16x32_f16(ah[mf], bl[nf], acc[mf][nf], 0, 0, 0);
                acc[mf][nf] = __builtin_amdgcn_mfma_f32_16x16x32_f16(al[mf], bh[nf], acc[mf][nf], 0, 0, 0);
            }
        __syncthreads();
    }

    // scores + per-row argmin over this block's 256 codes.
    // After the loop-final barrier all LDS reads are done -> reuse Ah/Al as scratch.
    float* sminV = (float*)Ah;  // [4][128]
    int* sminI = (int*)Al;      // [4][128]

    float esq[4];
#pragma unroll
    for (int nf = 0; nf < 4; ++nf) esq[nf] = e_sq[c0 + wn * 64 + nf * 16 + l16];

#pragma unroll
    for (int mf = 0; mf < 4; ++mf) {
#pragma unroll
        for (int rg = 0; rg < 4; ++rg) {
            float bestV = 3.4e38f;
            int bestI = 0;
#pragma unroll
            for (int nf = 0; nf < 4; ++nf) {
                float v = esq[nf] - 2.0f * acc[mf][nf][rg];
                int ci = c0 + wn * 64 + nf * 16 + l16;
                if (v < bestV || (v == bestV && ci < bestI)) { bestV = v; bestI = ci; }
            }
#pragma unroll
            for (int off = 1; off < 16; off <<= 1) {
                float vv = __shfl_xor(bestV, off);
                int ii = __shfl_xor(bestI, off);
                if (vv < bestV || (vv == bestV && ii < bestI)) { bestV = vv; bestI = ii; }
            }
            if (l16 == 0) {
                int rloc = wm * 64 + mf * 16 + lhi * 4 + rg;
                sminV[wn * 128 + rloc] = bestV;
                sminI[wn * 128 + rloc] = bestI;
            }
        }
    }
    __syncthreads();
    if (t < 128) {
        float bestV = sminV[t];
        int bestI = sminI[t];
#pragma unroll
        for (int wn2 = 1; wn2 < 4; ++wn2) {
            float v = sminV[wn2 * 128 + t];
            int i2 = sminI[wn2 * 128 + t];
            if (v < bestV || (v == bestV && i2 < bestI)) { bestV = v; bestI = i2; }
        }
        partV[colTile * N_TOK + r0 + t] = bestV;
        partI[colTile * N_TOK + r0 + t] = bestI;
    }
}

// ---------------- K4a: combine partials -> final index -----------------------
__global__ void k_final_idx(const float* __restrict__ partV, const int* __restrict__ partI,
                            float* __restrict__ out2, int* __restrict__ idxI) {
    int n = blockIdx.x * 256 + threadIdx.x;
    float bestV = partV[n];
    int bestI = partI[n];
#pragma unroll
    for (int ct = 1; ct < 4; ++ct) {
        float v = partV[ct * N_TOK + n];
        int i2 = partI[ct * N_TOK + n];
        if (v < bestV || (v == bestV && i2 < bestI)) { bestV = v; bestI = i2; }
    }
    out2[n] = (float)bestI;
    idxI[n] = bestI;
}

// ---------------- K4b: quantized_flat[N,D] = embedding[idx] ------------------
__global__ void k_out1(const float* __restrict__ emb, const int* __restrict__ idxI,
                       float* __restrict__ out1) {
    int t = threadIdx.x;
    int r = blockIdx.x * 64 + (t >> 2), q = t & 3;
    int idx = idxI[r];
    const float* src = emb + (size_t)idx * DIM + q * 64;
    float* dst = out1 + (size_t)r * DIM + q * 64;
#pragma unroll
    for (int i = 0; i < 16; ++i)
        *(float4*)(dst + i * 4) = *(const float4*)(src + i * 4);
}

// ---------------- K4c: quantized[B,C,H,W] via LDS transpose ------------------
__global__ void k_out3(const float* __restrict__ emb, const int* __restrict__ idxI,
                       float* __restrict__ out3) {
    __shared__ float E[32][257];
    int blk = blockIdx.x;
    int b = blk >> 7, hwt = blk & 127;
    int hw0 = hwt * 32;
    int n0 = b * HWSZ + hw0;
    int t = threadIdx.x;
    {
        int r = t >> 3, oct = t & 7;
        int idx = idxI[n0 + r];
        const float* src = emb + (size_t)idx * DIM + oct * 32;
#pragma unroll
        for (int i = 0; i < 8; ++i) {
            float4 v = *(const float4*)(src + i * 4);
            E[r][oct * 32 + i * 4 + 0] = v.x;
            E[r][oct * 32 + i * 4 + 1] = v.y;
            E[r][oct * 32 + i * 4 + 2] = v.z;
            E[r][oct * 32 + i * 4 + 3] = v.w;
        }
    }
    __syncthreads();
    {
        int w = t >> 6, l = t & 63;
        int ch = l >> 5, hw = l & 31;
        float* dst = out3 + (size_t)b * DIM * HWSZ + hw0 + hw;
#pragma unroll
        for (int it = 0; it < 32; ++it) {
            int c = w * 64 + it * 2 + ch;
            dst[(size_t)c * HWSZ] = E[hw][c];
        }
    }
}

extern "C" void kernel_launch(void* const* d_in, const int* in_sizes, int n_in,
                              void* d_out, int out_size, void* d_ws, size_t ws_size,
                              hipStream_t stream) {
    const float* z = (const float*)d_in[0];
    const float* emb = (const float*)d_in[1];
    float* out = (float*)d_out;
    float* out0 = out;                    // encoded_flat  [65536,256]
    float* out1 = out + 16777216;         // quantized_flat[65536,256]
    float* out2 = out + 33554432;         // indices       [65536] (as float)
    float* out3 = out + 33619968;         // quantized     [16,256,64,64]

    char* ws = (char*)d_ws;
    _Float16* eBh = (_Float16*)(ws);                 // 1024*256 fp16 = 512 KB
    _Float16* eBl = (_Float16*)(ws + 524288);        // 512 KB
    float* e_sq = (float*)(ws + 1048576);            // 4 KB
    float* partV = (float*)(ws + 1052672);           // 4*65536 fp32 = 1 MB
    int* partI = (int*)(ws + 2101248);               // 1 MB
    int* idxI = (int*)(ws + 3149824);                // 256 KB

    k_prep<<<256, 256, 0, stream>>>(emb, eBh, eBl, e_sq);
    k_transpose<<<4096, 256, 0, stream>>>(z, out0);
    k_gemm_argmin<<<2048, 512, 0, stream>>>(out0, eBh, eBl, e_sq, partV, partI);
    k_final_idx<<<256, 256, 0, stream>>>(partV, partI, out2, idxI);
    k_out1<<<1024, 256, 0, stream>>>(emb, idxI, out1);
    k_out3<<<2048, 256, 0, stream>>>(emb, idxI, out3);
}

// Round 2
// 237.590 us; speedup vs baseline: 1.1082x; 1.1082x over previous
//
#include <hip/hip_runtime.h>
#include <hip/hip_bf16.h>

typedef _Float16 h8 __attribute__((ext_vector_type(8)));
typedef float f4 __attribute__((ext_vector_type(4)));

#define N_TOK 65536
#define DIM 256
#define KCODES 1024
#define HWSZ 4096

// async global->LDS, 16B per lane. LDS dest = wave-uniform base + lane*16.
__device__ __forceinline__ void gll16(const void* g, void* l) {
    __builtin_amdgcn_global_load_lds((const __attribute__((address_space(1))) void*)g,
                                     (__attribute__((address_space(3))) void*)l, 16, 0, 0);
}

// Fragment layout (both A and B operands, 16x16x32 f16 MFMA):
//   element (n, d) -> granule G = ((n>>4)*8 + (d>>5))*64 + ((d>>3)&3)*16 + (n&15),
//   half j = d&7 inside the 16B granule.
// A wave's ds_read_b128 then reads 64 consecutive granules -> conflict-free,
// and global_load_lds staging is linear.

// ---------------- K0a: embedding -> fragment-layout fp16 hi/lo ---------------
__global__ void k_prep_frag(const float* __restrict__ emb, _Float16* __restrict__ BhF,
                            _Float16* __restrict__ BlF) {
    int gi = blockIdx.x * 256 + threadIdx.x;      // granule index, 0..32767
    int kb = gi >> 9;
    int s = (gi >> 6) & 7;
    int dq = (gi >> 4) & 3;
    int r = gi & 15;
    int code = kb * 16 + r;
    int d0 = s * 32 + dq * 8;
    const float* src = emb + (size_t)code * DIM + d0;
    float4 x0 = *(const float4*)(src);
    float4 x1 = *(const float4*)(src + 4);
    float xs[8] = {x0.x, x0.y, x0.z, x0.w, x1.x, x1.y, x1.z, x1.w};
    h8 hi, lo;
#pragma unroll
    for (int j = 0; j < 8; ++j) {
        _Float16 h = (_Float16)xs[j];
        hi[j] = h;
        lo[j] = (_Float16)(xs[j] - (float)h);
    }
    *(h8*)(BhF + (size_t)gi * 8) = hi;
    *(h8*)(BlF + (size_t)gi * 8) = lo;
}

// ---------------- K0b: e_sq ---------------------------------------------------
__global__ void k_esq(const float* __restrict__ emb, float* __restrict__ e_sq) {
    int t = threadIdx.x;
    int code = blockIdx.x * 4 + (t >> 6);
    int l = t & 63;
    float4 v = *(const float4*)(emb + (size_t)code * DIM + l * 4);
    float s = v.x * v.x + v.y * v.y + v.z * v.z + v.w * v.w;
#pragma unroll
    for (int off = 32; off >= 1; off >>= 1) s += __shfl_xor(s, off);
    if (l == 0) e_sq[code] = s;
}

// ------- K1: transpose z[B,C,H,W] -> enc[N,C] + fragment fp16 hi/lo ----------
__global__ void k_transpose(const float* __restrict__ z, float* __restrict__ enc,
                            _Float16* __restrict__ AhF, _Float16* __restrict__ AlF) {
    __shared__ float T[64][65];
    int blk = blockIdx.x;
    int b = blk >> 8;
    int rem = blk & 255;
    int c0 = (rem >> 6) * 64;
    int hw0 = (rem & 63) * 64;
    int t = threadIdx.x;
    const float* zp = z + (size_t)b * DIM * HWSZ;
    {
        int hw4 = (t & 15) * 4, cl = t >> 4;
#pragma unroll
        for (int i = 0; i < 4; ++i) {
            int c = cl + i * 16;
            float4 v = *(const float4*)(zp + (size_t)(c0 + c) * HWSZ + hw0 + hw4);
            T[c][hw4 + 0] = v.x; T[c][hw4 + 1] = v.y;
            T[c][hw4 + 2] = v.z; T[c][hw4 + 3] = v.w;
        }
    }
    __syncthreads();
    // enc fp32 (output 0)
    {
        int c4 = (t & 15) * 4, hwl = t >> 4;
#pragma unroll
        for (int i = 0; i < 4; ++i) {
            int hw = hwl + i * 16;
            float4 v;
            v.x = T[c4 + 0][hw]; v.y = T[c4 + 1][hw];
            v.z = T[c4 + 2][hw]; v.w = T[c4 + 3][hw];
            *(float4*)(enc + (size_t)(b * HWSZ + hw0 + hw) * DIM + c0 + c4) = v;
        }
    }
    // fragment-layout fp16 hi/lo
    {
        int base_nb = b * 256 + (hw0 >> 4);
#pragma unroll
        for (int i = 0; i < 2; ++i) {
            int gidx = i * 256 + t;
            int nbi = gidx >> 7;
            int si = (gidx >> 6) & 1;
            int dq = (gidx >> 4) & 3;
            int r = gidx & 15;
            int hwl = nbi * 16 + r;
            int cl = si * 32 + dq * 8;
            h8 hi, lo;
#pragma unroll
            for (int j = 0; j < 8; ++j) {
                float x = T[cl + j][hwl];
                _Float16 h = (_Float16)x;
                hi[j] = h;
                lo[j] = (_Float16)(x - (float)h);
            }
            size_t G = (((size_t)(base_nb + nbi) * 8) + (c0 >> 5) + si) * 64 + dq * 16 + r;
            *(h8*)(AhF + G * 8) = hi;
            *(h8*)(AlF + G * 8) = lo;
        }
    }
}

// ---------------- K2: GEMM (fp16 split, 3 passes) + fused argmin -------------
__global__ __launch_bounds__(512)
void k_gemm_argmin(const _Float16* __restrict__ AhF, const _Float16* __restrict__ AlF,
                   const _Float16* __restrict__ BhF, const _Float16* __restrict__ BlF,
                   const float* __restrict__ e_sq,
                   float* __restrict__ partV, int* __restrict__ partI) {
    __shared__ _Float16 sAh[4096];   // 8 KB  : 8 chunks of 1KB (nb-local)
    __shared__ _Float16 sAl[4096];   // 8 KB
    __shared__ _Float16 sBh[8192];   // 16 KB : 16 chunks (kb-local)
    __shared__ _Float16 sBl[8192];   // 16 KB

    int gid = blockIdx.x;
    int colTile = gid >> 9, rowTile = gid & 511;
    int r0 = rowTile * 128, c0 = colTile * 256;
    int t = threadIdx.x;
    int w = t >> 6, l = t & 63;
    int wm = w >> 2, wn = w & 3;
    int l16 = l & 15, lhi = l >> 4;

    const char* gAh = (const char*)AhF + (((size_t)(rowTile * 8 + w)) << 13) + (l << 4);
    const char* gAl = (const char*)AlF + (((size_t)(rowTile * 8 + w)) << 13) + (l << 4);
    const char* gBh0 = (const char*)BhF + (((size_t)(colTile * 16 + w)) << 13) + (l << 4);
    const char* gBh1 = gBh0 + (8ll << 13);
    const char* gBl0 = (const char*)BlF + (((size_t)(colTile * 16 + w)) << 13) + (l << 4);
    const char* gBl1 = gBl0 + (8ll << 13);
    char* lAh = (char*)sAh + (w << 10);
    char* lAl = (char*)sAl + (w << 10);
    char* lBh0 = (char*)sBh + (w << 10);
    char* lBh1 = (char*)sBh + ((8 + w) << 10);
    char* lBl0 = (char*)sBl + (w << 10);
    char* lBl1 = (char*)sBl + ((8 + w) << 10);

    f4 acc[4][4];
#pragma unroll
    for (int i = 0; i < 4; ++i)
#pragma unroll
        for (int j = 0; j < 4; ++j) acc[i][j] = (f4)0.0f;

    for (int s = 0; s < 8; ++s) {
        size_t so = (size_t)s << 10;
        gll16(gAh + so, lAh);
        gll16(gAl + so, lAl);
        gll16(gBh0 + so, lBh0);
        gll16(gBh1 + so, lBh1);
        gll16(gBl0 + so, lBl0);
        gll16(gBl1 + so, lBl1);
        __syncthreads();  // drains vmcnt(0) before s_barrier

        h8 ah[4], al[4], bh[4], bl[4];
#pragma unroll
        for (int mf = 0; mf < 4; ++mf) {
            ah[mf] = *(const h8*)(sAh + (((wm * 4 + mf) << 9) + (l << 3)));
            al[mf] = *(const h8*)(sAl + (((wm * 4 + mf) << 9) + (l << 3)));
        }
#pragma unroll
        for (int nf = 0; nf < 4; ++nf) {
            bh[nf] = *(const h8*)(sBh + (((wn * 4 + nf) << 9) + (l << 3)));
            bl[nf] = *(const h8*)(sBl + (((wn * 4 + nf) << 9) + (l << 3)));
        }
#pragma unroll
        for (int mf = 0; mf < 4; ++mf)
#pragma unroll
            for (int nf = 0; nf < 4; ++nf) {
                acc[mf][nf] = __builtin_amdgcn_mfma_f32_16x16x32_f16(ah[mf], bh[nf], acc[mf][nf], 0, 0, 0);
                acc[mf][nf] = __builtin_amdgcn_mfma_f32_16x16x32_f16(ah[mf], bl[nf], acc[mf][nf], 0, 0, 0);
                acc[mf][nf] = __builtin_amdgcn_mfma_f32_16x16x32_f16(al[mf], bh[nf], acc[mf][nf], 0, 0, 0);
            }
        __syncthreads();
    }

    // ---- scores + per-row argmin over this block's 256 codes ----
    float* sminV = (float*)sAh;  // [4][128]
    int* sminI = (int*)sAl;      // [4][128]

    float esq[4];
#pragma unroll
    for (int nf = 0; nf < 4; ++nf) esq[nf] = e_sq[c0 + wn * 64 + nf * 16 + l16];

#pragma unroll
    for (int mf = 0; mf < 4; ++mf) {
#pragma unroll
        for (int rg = 0; rg < 4; ++rg) {
            float bestV = 3.4e38f;
            int bestI = 0;
#pragma unroll
            for (int nf = 0; nf < 4; ++nf) {
                float v = esq[nf] - 2.0f * acc[mf][nf][rg];
                int ci = c0 + wn * 64 + nf * 16 + l16;
                if (v < bestV || (v == bestV && ci < bestI)) { bestV = v; bestI = ci; }
            }
#pragma unroll
            for (int off = 1; off < 16; off <<= 1) {
                float vv = __shfl_xor(bestV, off);
                int ii = __shfl_xor(bestI, off);
                if (vv < bestV || (vv == bestV && ii < bestI)) { bestV = vv; bestI = ii; }
            }
            if (l16 == 0) {
                int rloc = wm * 64 + mf * 16 + lhi * 4 + rg;
                sminV[wn * 128 + rloc] = bestV;
                sminI[wn * 128 + rloc] = bestI;
            }
        }
    }
    __syncthreads();
    if (t < 128) {
        float bestV = sminV[t];
        int bestI = sminI[t];
#pragma unroll
        for (int wn2 = 1; wn2 < 4; ++wn2) {
            float v = sminV[wn2 * 128 + t];
            int i2 = sminI[wn2 * 128 + t];
            if (v < bestV || (v == bestV && i2 < bestI)) { bestV = v; bestI = i2; }
        }
        partV[colTile * N_TOK + r0 + t] = bestV;
        partI[colTile * N_TOK + r0 + t] = bestI;
    }
}

// ---------------- K3a: combine partials -> final index -----------------------
__global__ void k_final_idx(const float* __restrict__ partV, const int* __restrict__ partI,
                            float* __restrict__ out2, int* __restrict__ idxI) {
    int n = blockIdx.x * 256 + threadIdx.x;
    float bestV = partV[n];
    int bestI = partI[n];
#pragma unroll
    for (int ct = 1; ct < 4; ++ct) {
        float v = partV[ct * N_TOK + n];
        int i2 = partI[ct * N_TOK + n];
        if (v < bestV || (v == bestV && i2 < bestI)) { bestV = v; bestI = i2; }
    }
    out2[n] = (float)bestI;
    idxI[n] = bestI;
}

// ---------------- K3b: quantized_flat[N,D] = embedding[idx] ------------------
__global__ void k_out1(const float* __restrict__ emb, const int* __restrict__ idxI,
                       float* __restrict__ out1) {
    int t = threadIdx.x;
    int r = blockIdx.x * 64 + (t >> 2), q = t & 3;
    int idx = idxI[r];
    const float* src = emb + (size_t)idx * DIM + q * 64;
    float* dst = out1 + (size_t)r * DIM + q * 64;
#pragma unroll
    for (int i = 0; i < 16; ++i)
        *(float4*)(dst + i * 4) = *(const float4*)(src + i * 4);
}

// ---------------- K3c: quantized[B,C,H,W] via LDS transpose ------------------
__global__ void k_out3(const float* __restrict__ emb, const int* __restrict__ idxI,
                       float* __restrict__ out3) {
    __shared__ float E[32][257];
    int blk = blockIdx.x;
    int b = blk >> 7, hwt = blk & 127;
    int hw0 = hwt * 32;
    int n0 = b * HWSZ + hw0;
    int t = threadIdx.x;
    {
        int r = t >> 3, oct = t & 7;
        int idx = idxI[n0 + r];
        const float* src = emb + (size_t)idx * DIM + oct * 32;
#pragma unroll
        for (int i = 0; i < 8; ++i) {
            float4 v = *(const float4*)(src + i * 4);
            E[r][oct * 32 + i * 4 + 0] = v.x;
            E[r][oct * 32 + i * 4 + 1] = v.y;
            E[r][oct * 32 + i * 4 + 2] = v.z;
            E[r][oct * 32 + i * 4 + 3] = v.w;
        }
    }
    __syncthreads();
    {
        int w = t >> 6, l = t & 63;
        int ch = l >> 5, hw = l & 31;
        float* dst = out3 + (size_t)b * DIM * HWSZ + hw0 + hw;
#pragma unroll
        for (int it = 0; it < 32; ++it) {
            int c = w * 64 + it * 2 + ch;
            dst[(size_t)c * HWSZ] = E[hw][c];
        }
    }
}

extern "C" void kernel_launch(void* const* d_in, const int* in_sizes, int n_in,
                              void* d_out, int out_size, void* d_ws, size_t ws_size,
                              hipStream_t stream) {
    const float* z = (const float*)d_in[0];
    const float* emb = (const float*)d_in[1];
    float* out = (float*)d_out;
    float* out0 = out;                    // encoded_flat  [65536,256]
    float* out1 = out + 16777216;         // quantized_flat[65536,256]
    float* out2 = out + 33554432;         // indices       [65536] (as float)
    float* out3 = out + 33619968;         // quantized     [16,256,64,64]

    // A-operand fp16 hi/lo scratch lives in the out1 region (written last by
    // k_out1, read only by k_gemm which runs before it). 32 MB + 32 MB = 64 MB.
    _Float16* AhF = (_Float16*)out1;
    _Float16* AlF = (_Float16*)(out1 + 8388608);

    char* ws = (char*)d_ws;
    _Float16* BhF = (_Float16*)(ws);                 // 512 KB
    _Float16* BlF = (_Float16*)(ws + 524288);        // 512 KB
    float* e_sq = (float*)(ws + 1048576);            // 4 KB
    float* partV = (float*)(ws + 1052672);           // 1 MB
    int* partI = (int*)(ws + 2101248);               // 1 MB
    int* idxI = (int*)(ws + 3149824);                // 256 KB

    k_prep_frag<<<128, 256, 0, stream>>>(emb, BhF, BlF);
    k_esq<<<256, 256, 0, stream>>>(emb, e_sq);
    k_transpose<<<4096, 256, 0, stream>>>(z, out0, AhF, AlF);
    k_gemm_argmin<<<2048, 512, 0, stream>>>(AhF, AlF, BhF, BlF, e_sq, partV, partI);
    k_final_idx<<<256, 256, 0, stream>>>(partV, partI, out2, idxI);
    k_out1<<<1024, 256, 0, stream>>>(emb, idxI, out1);
    k_out3<<<2048, 256, 0, stream>>>(emb, idxI, out3);
}